// Round 1
// baseline (134.598 us; speedup 1.0000x reference)
//
#include <hip/hip_runtime.h>
#include <stdint.h>
#include <stddef.h>

// Attention: B=256,H=32,S=16,D=64, scale 1/sqrt(8), +ones mask (softmax no-op),
// softmax, dropout p=0.3 with JAX threefry (key 42, partitionable scheme), then @V.
// One wave per (b,h). QK^T via bf16 MFMA with hi/lo split (f32-accurate),
// softmax via 16-lane shuffles, dropout mask computed per-element to bit-match
// jax.random.bernoulli(jax.random.key(42), 0.7, (B,H,S,S)).

typedef __attribute__((ext_vector_type(8))) short short8;
typedef __attribute__((ext_vector_type(4))) float f32x4;

__device__ __forceinline__ unsigned short bf16_rne(float f) {
  unsigned u = __builtin_bit_cast(unsigned, f);
  unsigned r = 0x7FFFu + ((u >> 16) & 1u);
  return (unsigned short)((u + r) >> 16);
}
__device__ __forceinline__ float bf16_to_f32(unsigned short h) {
  unsigned u = ((unsigned)h) << 16;
  return __builtin_bit_cast(float, u);
}

// JAX threefry2x32, key=(0,42), counter words (x0=0, x1=idx); returns o0^o1
// (the partitionable 32-bit draw).
__device__ __forceinline__ unsigned threefry_bits(unsigned idx) {
  const unsigned k0 = 0u, k1 = 42u;
  const unsigned k2 = k0 ^ k1 ^ 0x1BD11BDAu;
  unsigned x0 = k0;        // 0 + ks[0]
  unsigned x1 = idx + k1;  // idx + ks[1]
#define TF_ROUND(r) { x0 += x1; x1 = (x1 << (r)) | (x1 >> (32 - (r))); x1 ^= x0; }
  TF_ROUND(13) TF_ROUND(15) TF_ROUND(26) TF_ROUND(6)
  x0 += k1; x1 += k2 + 1u;
  TF_ROUND(17) TF_ROUND(29) TF_ROUND(16) TF_ROUND(24)
  x0 += k2; x1 += k0 + 2u;
  TF_ROUND(13) TF_ROUND(15) TF_ROUND(26) TF_ROUND(6)
  x0 += k0; x1 += k1 + 3u;
  TF_ROUND(17) TF_ROUND(29) TF_ROUND(16) TF_ROUND(24)
  x0 += k1; x1 += k2 + 4u;
  TF_ROUND(13) TF_ROUND(15) TF_ROUND(26) TF_ROUND(6)
  x0 += k2; x1 += k0 + 5u;
#undef TF_ROUND
  return x0 ^ x1;
}

__device__ __forceinline__ void cvt_hilo8(const float* x, short8& hi, short8& lo) {
#pragma unroll
  for (int i = 0; i < 8; i++) {
    float f = x[i];
    unsigned short hs = bf16_rne(f);
    float hf = bf16_to_f32(hs);
    hi[i] = (short)hs;
    lo[i] = (short)bf16_rne(f - hf);
  }
}

__global__ __launch_bounds__(256) void attn_kernel(
    const float* __restrict__ q, const float* __restrict__ k,
    const float* __restrict__ v, float* __restrict__ out) {
  // per-wave P tile for C-layout -> A-layout relayout; stride 20 floats (80B,
  // 16B-aligned rows, breaks power-of-2 bank stride)
  __shared__ float plds[4][16 * 20];

  const int lane = threadIdx.x & 63;
  const int w = threadIdx.x >> 6;
  const int bh = blockIdx.x * 4 + w;      // 0..8191
  const int c = lane & 15;                // row for A/B frags; col in C layout
  const int g = lane >> 4;                // quad 0..3

  const float* qp = q + (size_t)bh * 1024;
  const float* kp = k + (size_t)bh * 1024;
  const float* vp = v + (size_t)bh * 1024;
  float* op = out + (size_t)bh * 1024;

  // ---- load Q,K fragment source: row c, cols g*8..g*8+7 and +32 ----
  float qbuf[16], kbuf[16];
  const float* qrow = qp + c * 64 + g * 8;
  const float* krow = kp + c * 64 + g * 8;
#pragma unroll
  for (int h = 0; h < 2; h++) {
    float4 a = ((const float4*)(qrow + h * 32))[0];
    float4 b = ((const float4*)(qrow + h * 32))[1];
    qbuf[h * 8 + 0] = a.x; qbuf[h * 8 + 1] = a.y; qbuf[h * 8 + 2] = a.z; qbuf[h * 8 + 3] = a.w;
    qbuf[h * 8 + 4] = b.x; qbuf[h * 8 + 5] = b.y; qbuf[h * 8 + 6] = b.z; qbuf[h * 8 + 7] = b.w;
    float4 e = ((const float4*)(krow + h * 32))[0];
    float4 f = ((const float4*)(krow + h * 32))[1];
    kbuf[h * 8 + 0] = e.x; kbuf[h * 8 + 1] = e.y; kbuf[h * 8 + 2] = e.z; kbuf[h * 8 + 3] = e.w;
    kbuf[h * 8 + 4] = f.x; kbuf[h * 8 + 5] = f.y; kbuf[h * 8 + 6] = f.z; kbuf[h * 8 + 7] = f.w;
  }

  short8 qhi0, qlo0, qhi1, qlo1, khi0, klo0, khi1, klo1;
  cvt_hilo8(qbuf, qhi0, qlo0);
  cvt_hilo8(qbuf + 8, qhi1, qlo1);
  cvt_hilo8(kbuf, khi0, klo0);
  cvt_hilo8(kbuf + 8, khi1, klo1);

  // ---- scores = Q K^T in (near) f32 precision: hi*hi + lo*hi + hi*lo ----
  f32x4 acc = {0.f, 0.f, 0.f, 0.f};
  acc = __builtin_amdgcn_mfma_f32_16x16x32_bf16(qhi0, khi0, acc, 0, 0, 0);
  acc = __builtin_amdgcn_mfma_f32_16x16x32_bf16(qhi1, khi1, acc, 0, 0, 0);
  acc = __builtin_amdgcn_mfma_f32_16x16x32_bf16(qlo0, khi0, acc, 0, 0, 0);
  acc = __builtin_amdgcn_mfma_f32_16x16x32_bf16(qlo1, khi1, acc, 0, 0, 0);
  acc = __builtin_amdgcn_mfma_f32_16x16x32_bf16(qhi0, klo0, acc, 0, 0, 0);
  acc = __builtin_amdgcn_mfma_f32_16x16x32_bf16(qhi1, klo1, acc, 0, 0, 0);

  // C layout: acc[t] = S[4g+t][c]. Softmax over c (16 lanes of this quad-group).
  const float SCALE = 0.35355339059327373f;  // 1/sqrt(8); +1 mask cancels in softmax
  float ad[4];
#pragma unroll
  for (int t = 0; t < 4; t++) {
    float sv = acc[t] * SCALE;
    float mx = sv;
#pragma unroll
    for (int msk = 1; msk < 16; msk <<= 1) mx = fmaxf(mx, __shfl_xor(mx, msk));
    float p = __expf(sv - mx);
    float sum = p;
#pragma unroll
    for (int msk = 1; msk < 16; msk <<= 1) sum += __shfl_xor(sum, msk);
    float aval = p / sum;
    // dropout: flat index over (B,H,S,S)
    unsigned idx = ((unsigned)bh << 8) + (unsigned)((4 * g + t) * 16 + c);
    unsigned bits = threefry_bits(idx);
    float u = __builtin_bit_cast(float, 0x3F800000u | (bits >> 9)) - 1.0f;
    ad[t] = (u < 0.7f) ? aval * (1.0f / 0.7f) : 0.0f;
  }

  // ---- relayout P (C layout -> A layout) through LDS ----
  float* pb = plds[w];
#pragma unroll
  for (int t = 0; t < 4; t++) pb[(4 * g + t) * 20 + c] = ad[t];
  __syncthreads();

  short8 pa = {0, 0, 0, 0, 0, 0, 0, 0};
  if (g < 2) {
    const float* ps = pb + c * 20 + g * 8;  // row c, k = g*8+j  (j<16 valid)
#pragma unroll
    for (int j = 0; j < 8; j++) pa[j] = (short)bf16_rne(ps[j]);
  }

  // ---- O = P @ V, 4 n-tiles of 16; K padded 16->32 with zeros ----
  f32x4 oacc[4];
#pragma unroll
  for (int nt = 0; nt < 4; nt++) {
    short8 vb = {0, 0, 0, 0, 0, 0, 0, 0};
    if (g < 2) {
#pragma unroll
      for (int j = 0; j < 8; j++)
        vb[j] = (short)bf16_rne(vp[(g * 8 + j) * 64 + nt * 16 + c]);
    }
    f32x4 z = {0.f, 0.f, 0.f, 0.f};
    oacc[nt] = __builtin_amdgcn_mfma_f32_16x16x32_bf16(pa, vb, z, 0, 0, 0);
  }

#pragma unroll
  for (int nt = 0; nt < 4; nt++)
#pragma unroll
    for (int t = 0; t < 4; t++)
      op[(4 * g + t) * 64 + nt * 16 + c] = oacc[nt][t];
}

extern "C" void kernel_launch(void* const* d_in, const int* in_sizes, int n_in,
                              void* d_out, int out_size, void* d_ws, size_t ws_size,
                              hipStream_t stream) {
  const float* q = (const float*)d_in[0];
  const float* k = (const float*)d_in[1];
  const float* v = (const float*)d_in[2];
  float* out = (float*)d_out;
  // 8192 (b,h) heads, one wave each, 4 waves per block
  attn_kernel<<<2048, 256, 0, stream>>>(q, k, v, out);
}

// Round 2
// 132.109 us; speedup vs baseline: 1.0188x; 1.0188x over previous
//
#include <hip/hip_runtime.h>
#include <stdint.h>
#include <stddef.h>

// Attention B=256,H=32,S=16,D=64: softmax(QK^T/sqrt(8) + ones) with JAX
// threefry dropout p=0.3 (key 42, partitionable), then @V.
// One wave per (b,h) head. QK^T via bf16 MFMA hi/lo split (f32-accurate).
// R1: V issued early as 4 coalesced float4 loads -> per-wave LDS staging
// (overlaps the QK/softmax chain), PV frags fed from LDS scalars.

typedef __attribute__((ext_vector_type(8))) short short8;
typedef __attribute__((ext_vector_type(4))) float f32x4;

__device__ __forceinline__ unsigned short bf16_rne(float f) {
  unsigned u = __builtin_bit_cast(unsigned, f);
  unsigned r = 0x7FFFu + ((u >> 16) & 1u);
  return (unsigned short)((u + r) >> 16);
}
__device__ __forceinline__ float bf16_to_f32(unsigned short h) {
  unsigned u = ((unsigned)h) << 16;
  return __builtin_bit_cast(float, u);
}

// JAX threefry2x32, key=(0,42), counter (0, idx); draw = x0^x1. Bit-exact vs
// jax.random.bernoulli(jax.random.key(42), ...) — verified R0 (absmax 0.031).
__device__ __forceinline__ unsigned threefry_bits(unsigned idx) {
  const unsigned k0 = 0u, k1 = 42u;
  const unsigned k2 = k0 ^ k1 ^ 0x1BD11BDAu;
  unsigned x0 = k0;
  unsigned x1 = idx + k1;
#define TF_ROUND(r) { x0 += x1; x1 = (x1 << (r)) | (x1 >> (32 - (r))); x1 ^= x0; }
  TF_ROUND(13) TF_ROUND(15) TF_ROUND(26) TF_ROUND(6)
  x0 += k1; x1 += k2 + 1u;
  TF_ROUND(17) TF_ROUND(29) TF_ROUND(16) TF_ROUND(24)
  x0 += k2; x1 += k0 + 2u;
  TF_ROUND(13) TF_ROUND(15) TF_ROUND(26) TF_ROUND(6)
  x0 += k0; x1 += k1 + 3u;
  TF_ROUND(17) TF_ROUND(29) TF_ROUND(16) TF_ROUND(24)
  x0 += k1; x1 += k2 + 4u;
  TF_ROUND(13) TF_ROUND(15) TF_ROUND(26) TF_ROUND(6)
  x0 += k2; x1 += k0 + 5u;
#undef TF_ROUND
  return x0 ^ x1;
}

__device__ __forceinline__ void cvt_hilo_f4(float4 a, float4 b, short8& hi, short8& lo) {
  float x[8] = {a.x, a.y, a.z, a.w, b.x, b.y, b.z, b.w};
#pragma unroll
  for (int i = 0; i < 8; i++) {
    float f = x[i];
    unsigned short hs = bf16_rne(f);
    hi[i] = (short)hs;
    lo[i] = (short)bf16_rne(f - bf16_to_f32(hs));
  }
}

__global__ __launch_bounds__(256) void attn_kernel(
    const float* __restrict__ q, const float* __restrict__ k,
    const float* __restrict__ v, float* __restrict__ out) {
  __shared__ float vst[4][16 * 64];  // per-wave staged V (4 KB)
  __shared__ float pst[4][16 * 20];  // per-wave P relayout tile (pad 20)

  const int lane = threadIdx.x & 63;
  const int w = threadIdx.x >> 6;
  const int bh = blockIdx.x * 4 + w;
  const int c = lane & 15;  // A/B frag row; C-layout col
  const int g = lane >> 4;  // quad

  const float* qp = q + (size_t)bh * 1024;
  const float* kp = k + (size_t)bh * 1024;
  const float* vp = v + (size_t)bh * 1024;
  float* op = out + (size_t)bh * 1024;

  // ---- issue ALL global loads up front ----
  // Q/K frag sources: row c, cols g*8..+7 and +32 (wave covers full 4 KB block)
  const float4* qrow = (const float4*)(qp + c * 64 + g * 8);
  const float4* krow = (const float4*)(kp + c * 64 + g * 8);
  float4 qv0 = qrow[0], qv1 = qrow[1], qv2 = qrow[8], qv3 = qrow[9];
  float4 kv0 = krow[0], kv1 = krow[1], kv2 = krow[8], kv3 = krow[9];
  // V staging: fully coalesced, 4 x (64 lanes x 16B) = 4 KB
  const float4* vsrc = (const float4*)vp;
  float4 vt0 = vsrc[lane], vt1 = vsrc[64 + lane], vt2 = vsrc[128 + lane], vt3 = vsrc[192 + lane];

  // ---- Q/K hi/lo bf16 split ----
  short8 qhi0, qlo0, qhi1, qlo1, khi0, klo0, khi1, klo1;
  cvt_hilo_f4(qv0, qv1, qhi0, qlo0);
  cvt_hilo_f4(qv2, qv3, qhi1, qlo1);
  cvt_hilo_f4(kv0, kv1, khi0, klo0);
  cvt_hilo_f4(kv2, kv3, khi1, klo1);

  // ---- scores = Q K^T: hi*hi + lo*hi + hi*lo ----
  f32x4 acc = {0.f, 0.f, 0.f, 0.f};
  acc = __builtin_amdgcn_mfma_f32_16x16x32_bf16(qhi0, khi0, acc, 0, 0, 0);
  acc = __builtin_amdgcn_mfma_f32_16x16x32_bf16(qhi1, khi1, acc, 0, 0, 0);
  acc = __builtin_amdgcn_mfma_f32_16x16x32_bf16(qlo0, khi0, acc, 0, 0, 0);
  acc = __builtin_amdgcn_mfma_f32_16x16x32_bf16(qlo1, khi1, acc, 0, 0, 0);
  acc = __builtin_amdgcn_mfma_f32_16x16x32_bf16(qhi0, klo0, acc, 0, 0, 0);
  acc = __builtin_amdgcn_mfma_f32_16x16x32_bf16(qhi1, klo1, acc, 0, 0, 0);

  // C layout: acc[t] = S[4g+t][c]; softmax across c (16-lane groups).
  const float SCALE = 0.35355339059327373f;  // +ones mask cancels in softmax
  float ad[4];
#pragma unroll
  for (int t = 0; t < 4; t++) {
    float sv = acc[t] * SCALE;
    float mx = sv;
#pragma unroll
    for (int msk = 1; msk < 16; msk <<= 1) mx = fmaxf(mx, __shfl_xor(mx, msk));
    float p = __expf(sv - mx);
    float sum = p;
#pragma unroll
    for (int msk = 1; msk < 16; msk <<= 1) sum += __shfl_xor(sum, msk);
    float aval = p / sum;
    unsigned idx = ((unsigned)bh << 8) + (unsigned)((4 * g + t) * 16 + c);
    unsigned bits = threefry_bits(idx);
    float u = __builtin_bit_cast(float, 0x3F800000u | (bits >> 9)) - 1.0f;
    ad[t] = (u < 0.7f) ? aval * (1.0f / 0.7f) : 0.0f;
  }

  // ---- stage V + P into LDS, one barrier ----
  float4* vw = (float4*)vst[w];
  vw[lane] = vt0; vw[64 + lane] = vt1; vw[128 + lane] = vt2; vw[192 + lane] = vt3;
  float* pb = pst[w];
#pragma unroll
  for (int t = 0; t < 4; t++) pb[(4 * g + t) * 20 + c] = ad[t];
  __syncthreads();

  // ---- P in A layout (k = g*8+j, valid k<16 -> g<2), V frags from LDS ----
  short8 pa = {0, 0, 0, 0, 0, 0, 0, 0};
  if (g < 2) {
    const float* ps = pb + c * 20 + g * 8;
#pragma unroll
    for (int j = 0; j < 8; j++) pa[j] = (short)bf16_rne(ps[j]);
  }

  const float* vb_base = vst[w];
  f32x4 oacc[4];
#pragma unroll
  for (int nt = 0; nt < 4; nt++) {
    short8 vb = {0, 0, 0, 0, 0, 0, 0, 0};
    if (g < 2) {
#pragma unroll
      for (int j = 0; j < 8; j++)
        vb[j] = (short)bf16_rne(vb_base[(g * 8 + j) * 64 + nt * 16 + c]);
    }
    f32x4 z = {0.f, 0.f, 0.f, 0.f};
    oacc[nt] = __builtin_amdgcn_mfma_f32_16x16x32_bf16(pa, vb, z, 0, 0, 0);
  }

#pragma unroll
  for (int nt = 0; nt < 4; nt++)
#pragma unroll
    for (int t = 0; t < 4; t++)
      op[(4 * g + t) * 64 + nt * 16 + c] = oacc[nt][t];
}

extern "C" void kernel_launch(void* const* d_in, const int* in_sizes, int n_in,
                              void* d_out, int out_size, void* d_ws, size_t ws_size,
                              hipStream_t stream) {
  const float* q = (const float*)d_in[0];
  const float* k = (const float*)d_in[1];
  const float* v = (const float*)d_in[2];
  float* out = (float*)d_out;
  attn_kernel<<<2048, 256, 0, stream>>>(q, k, v, out);
}